// Round 4
// baseline (1004.465 us; speedup 1.0000x reference)
//
#include <hip/hip_runtime.h>
#include <math.h>
#include <stdint.h>

#define D_  1024
#define T_  1024
#define H_  8
#define HD_ 128
#define L_  4
#define V_  32000
#define M_  2048   // B*T

typedef __attribute__((ext_vector_type(4))) float f32x4;
typedef __attribute__((ext_vector_type(4))) short s16x4;
typedef __attribute__((ext_vector_type(8))) short s16x8;
typedef unsigned short u16;

__device__ __forceinline__ u16 f2bf(float f) {
  union { float f; uint32_t u; } c; c.f = f;
  uint32_t r = c.u + 0x7fffu + ((c.u >> 16) & 1u);   // RTN-even
  return (u16)(r >> 16);
}
__device__ __forceinline__ float bf2f(u16 h) {
  union { uint32_t u; float f; } c; c.u = ((uint32_t)h) << 16;
  return c.f;
}
__device__ __forceinline__ float gelu_f(float x) {
  return 0.5f * x * (1.0f + erff(x * 0.70710678118654752f));
}

// async global->LDS, 16B per lane. LDS dest is wave-uniform base (HW adds
// lane*16); global ptr is per-lane. [guide §5, m97/m104]
__device__ __forceinline__ void gload16(const u16* g, u16* l) {
  __builtin_amdgcn_global_load_lds(
      (const __attribute__((address_space(1))) void*)(uintptr_t)g,
      (__attribute__((address_space(3))) void*)(uint32_t)(uintptr_t)l,
      16, 0, 0);
}

// ---------------------------------------------------------------------------
// Transpose-convert: in [R][C] (f32 if INF32 else bf16) -> out bf16 [C][R].
// 64x64 tiles via LDS. Grid: (C/64, R/64, Z).
// ---------------------------------------------------------------------------
template<int INF32>
__global__ __launch_bounds__(256)
void convT_kernel(const void* __restrict__ inv, u16* __restrict__ out,
                  int ldin, int ldout, long inZ, long outZ)
{
  __shared__ __align__(16) u16 tile[64][72];
  const int c0 = blockIdx.x << 6, r0 = blockIdx.y << 6;
  const int t = threadIdx.x;
  const int rr = t >> 2, cs = (t & 3) << 4;
  u16 tmp[16];
  if (INF32) {
    const float* in = (const float*)inv + (size_t)blockIdx.z * inZ;
    const float* p = in + (size_t)(r0 + rr) * ldin + c0 + cs;
#pragma unroll
    for (int q = 0; q < 4; ++q) {
      f32x4 v = *(const f32x4*)(p + q * 4);
#pragma unroll
      for (int j = 0; j < 4; ++j) tmp[q * 4 + j] = f2bf(v[j]);
    }
  } else {
    const u16* in = (const u16*)inv + (size_t)blockIdx.z * inZ;
    const u16* p = in + (size_t)(r0 + rr) * ldin + c0 + cs;
    s16x8 v0 = *(const s16x8*)(p);
    s16x8 v1 = *(const s16x8*)(p + 8);
#pragma unroll
    for (int j = 0; j < 8; ++j) { tmp[j] = (u16)v0[j]; tmp[8 + j] = (u16)v1[j]; }
  }
  *(s16x8*)&tile[rr][cs]     = *(const s16x8*)tmp;
  *(s16x8*)&tile[rr][cs + 8] = *(const s16x8*)(tmp + 8);
  __syncthreads();
  const int cr = t >> 2, rs = (t & 3) << 4;
  u16 o[16];
#pragma unroll
  for (int j = 0; j < 16; ++j) o[j] = tile[rs + j][cr];
  u16* op = out + (size_t)blockIdx.z * outZ + (size_t)(c0 + cr) * ldout + r0 + rs;
  *(s16x8*)op       = *(const s16x8*)o;
  *(s16x8*)(op + 8) = *(const s16x8*)(o + 8);
}

// ---------------------------------------------------------------------------
// bf16 MFMA GEMM (2-phase m97 structure) + T1 XCD swizzle.
// A bf16 [M][K] (lda), Bw bf16 [N][K] (ldb). BK=32, BN=128, TM in {64,128}.
// OUT: 0 = bf16, 1 = f32, 2 = f32 + res.
// NOTE: total grid blocks must be a multiple of 8 (bijective XCD swizzle).
// ---------------------------------------------------------------------------
template<int TM, int ACT, int BIAS, int OUT>
__global__ __launch_bounds__(256)
void gemm2(const u16* __restrict__ A, const u16* __restrict__ Bw,
           const float* __restrict__ bias, const float* __restrict__ res,
           void* __restrict__ Cv,
           int K, int lda, int ldb, int ldc, float scale)
{
  static_assert(TM == 64 || TM == 128, "tile");
  constexpr int WN  = (TM == 128) ? 2 : 4;
  constexpr int WNW = 128 / WN;
  constexpr int NJ  = WNW / 16;
  constexpr int AR  = TM / 64;

  const int gx = gridDim.x, gy = gridDim.y;
  int flat = blockIdx.y * gx + blockIdx.x;
  const int nwg = gx * gy;
  int swz = (flat & 7) * (nwg >> 3) + (flat >> 3);
  const int bx = swz % gx;
  const int by = swz / gx;

  const int m0 = bx * TM, n0 = by * 128;
  const int ktiles = K >> 5;

  __shared__ __align__(16) u16 As[2][TM * 32];
  __shared__ __align__(16) u16 Bs[2][128 * 32];

  const int tid = threadIdx.x, lane = tid & 63, wave = tid >> 6;
  const int wm = wave / WN, wn = wave % WN;
  const int l15 = lane & 15, l4 = lane >> 4;
  const int srow = lane >> 2, scol = (lane & 3) << 3;

  f32x4 acc[4][NJ];
  const f32x4 z4 = {0.f, 0.f, 0.f, 0.f};
#pragma unroll
  for (int i = 0; i < 4; ++i)
#pragma unroll
    for (int j = 0; j < NJ; ++j) acc[i][j] = z4;

  auto stage = [&](int kt, int buf) {
    const int kc = (kt << 5) + scol;
#pragma unroll
    for (int r = 0; r < AR; ++r) {
      const int row = r * 64 + wave * 16;
      gload16(A + (size_t)(m0 + row + srow) * lda + kc, &As[buf][row * 32]);
    }
#pragma unroll
    for (int r = 0; r < 2; ++r) {
      const int row = r * 64 + wave * 16;
      gload16(Bw + (size_t)(n0 + row + srow) * ldb + kc, &Bs[buf][row * 32]);
    }
  };

  stage(0, 0);
  __syncthreads();

  for (int kt = 0; kt < ktiles; ++kt) {
    const int buf = kt & 1;
    if (kt + 1 < ktiles) stage(kt + 1, buf ^ 1);
    const u16* ap = &As[buf][(wm * 64 + l15) * 32 + (l4 << 3)];
    const u16* bp = &Bs[buf][(wn * WNW + l15) * 32 + (l4 << 3)];
    s16x8 af[4], bf[NJ];
#pragma unroll
    for (int i = 0; i < 4; ++i) af[i] = *(const s16x8*)(ap + i * (16 * 32));
#pragma unroll
    for (int j = 0; j < NJ; ++j) bf[j] = *(const s16x8*)(bp + j * (16 * 32));
#pragma unroll
    for (int i = 0; i < 4; ++i)
#pragma unroll
      for (int j = 0; j < NJ; ++j)
        acc[i][j] = __builtin_amdgcn_mfma_f32_16x16x32_bf16(af[i], bf[j], acc[i][j], 0, 0, 0);
    __syncthreads();
  }

  // C/D lane map: col = lane&15, row = (lane>>4)*4 + r  [m89-verified]
  float* Cf = (float*)Cv;
  u16*   Ch = (u16*)Cv;
#pragma unroll
  for (int i = 0; i < 4; ++i) {
    const int row0 = m0 + wm * 64 + i * 16 + l4 * 4;
#pragma unroll
    for (int j = 0; j < NJ; ++j) {
      const int col = n0 + wn * WNW + j * 16 + l15;
      const float bv = BIAS ? bias[col] : 0.0f;
#pragma unroll
      for (int r = 0; r < 4; ++r) {
        float v = acc[i][j][r] * scale + bv;
        if (ACT) v = gelu_f(v);
        const size_t idx = (size_t)(row0 + r) * ldc + col;
        if (OUT == 0)      Ch[idx] = f2bf(v);
        else if (OUT == 1) Cf[idx] = v;
        else               Cf[idx] = v + res[idx];
      }
    }
  }
}

// ---------------------------------------------------------------------------
// Fused causal flash attention. Grid (16 qtiles, 16 bh), 256 threads.
// Per block: QBLK=64 q-rows (4 waves x 16), KV tiles of 64, kt <= qb.
// S^T = mfma(K, Q) so lane holds scores for q = lane&15 (lane-local softmax).
// P -> LDS (bf16, swizzled) -> PV with B-frags from swizzled Vt tile.
// Outputs bf16 into xo[B*T][D].
// ---------------------------------------------------------------------------
__global__ __launch_bounds__(256)
void flash_attn(const u16* __restrict__ qkv, const u16* __restrict__ Vt,
                u16* __restrict__ xo)
{
  const int qb = 15 - blockIdx.x;       // descending work order
  const int z  = blockIdx.y;            // b*8 + h
  const int b  = z >> 3, hh = z & 7;

  __shared__ __align__(16) u16 Ks[64 * 128];   // [k][d], 16B-unit XOR swizzle
  __shared__ __align__(16) u16 Vs[128 * 64];   // [d][k], swizzled
  __shared__ __align__(16) u16 Ps[64 * 80];    // [w*16+q][k], swizzled

  const int tid = threadIdx.x, lane = tid & 63, w = tid >> 6;
  const int l15 = lane & 15, l4 = lane >> 4;
  const float iscale = 0.08838834764831845f;   // 1/sqrt(128)

  const int qrow = qb * 64 + w * 16 + l15;     // this lane's q (B-frag row)
  const u16* qptr = qkv + ((size_t)(b * T_) + qrow) * (3 * D_) + hh * HD_;

  s16x8 bQ[4];
#pragma unroll
  for (int ks = 0; ks < 4; ++ks)
    bQ[ks] = *(const s16x8*)(qptr + ks * 32 + l4 * 8);

  f32x4 O[8];
#pragma unroll
  for (int i = 0; i < 8; ++i) O[i] = {0.f, 0.f, 0.f, 0.f};
  float m_run = -1e30f, l_run = 0.f;

  const int ntiles = qb + 1;
  for (int kt = 0; kt < ntiles; ++kt) {
    __syncthreads();
    // ---- stage K tile [64][128] (swizzled) ----
    {
      const int r = tid >> 2, c = (tid & 3) << 5;
      const u16* src = qkv + ((size_t)(b * T_) + kt * 64 + r) * (3 * D_) + D_ + hh * HD_ + c;
#pragma unroll
      for (int u = 0; u < 4; ++u) {
        s16x8 v = *(const s16x8*)(src + u * 8);
        const int dblk = (c >> 3) + u;
        *(s16x8*)&Ks[r * 128 + ((dblk ^ (r & 7)) << 3)] = v;
      }
      // ---- stage V tile from Vt [z-row d][t] -> Vs [d][64k] (swizzled) ----
      const int d = tid >> 1, kc0 = (tid & 1) << 5;
      const u16* vsrc = Vt + ((size_t)z * HD_ + d) * T_ + kt * 64 + kc0;
#pragma unroll
      for (int u = 0; u < 4; ++u) {
        s16x8 v = *(const s16x8*)(vsrc + u * 8);
        const int kblk = (kc0 >> 3) + u;
        *(s16x8*)&Vs[d * 64 + ((kblk ^ (d & 7)) << 3)] = v;
      }
    }
    __syncthreads();

    // ---- S^T = K @ Q : D[64k][16q]; lane: q = l15, k = 16*mf + 4*l4 + r ----
    f32x4 st[4];
#pragma unroll
    for (int mf = 0; mf < 4; ++mf) st[mf] = {0.f, 0.f, 0.f, 0.f};
#pragma unroll
    for (int ks = 0; ks < 4; ++ks) {
      s16x8 aK[4];
#pragma unroll
      for (int mf = 0; mf < 4; ++mf) {
        const int r = mf * 16 + l15;
        aK[mf] = *(const s16x8*)&Ks[r * 128 + ((((ks << 2) + l4) ^ (r & 7)) << 3)];
      }
#pragma unroll
      for (int mf = 0; mf < 4; ++mf)
        st[mf] = __builtin_amdgcn_mfma_f32_16x16x32_bf16(aK[mf], bQ[ks], st[mf], 0, 0, 0);
    }

    // ---- online softmax (per lane: 16 scores of q-row l15) ----
    const bool diag = (kt == qb);
    float sv[16];
    float mx = -1e30f;
#pragma unroll
    for (int mf = 0; mf < 4; ++mf)
#pragma unroll
      for (int r = 0; r < 4; ++r) {
        float s = st[mf][r] * iscale;
        if (diag) {
          const int k = kt * 64 + mf * 16 + l4 * 4 + r;
          if (k > qrow) s = -1e30f;
        }
        sv[mf * 4 + r] = s;
        mx = fmaxf(mx, s);
      }
    mx = fmaxf(mx, __shfl_xor(mx, 16));
    mx = fmaxf(mx, __shfl_xor(mx, 32));
    const float m_new = fmaxf(m_run, mx);
    const float sc_old = __expf(m_run - m_new);
    float psum = 0.f;
    u16 pb[16];
#pragma unroll
    for (int j = 0; j < 16; ++j) {
      const float p = __expf(sv[j] - m_new);
      psum += p;
      pb[j] = f2bf(p);
    }
    psum += __shfl_xor(psum, 16);
    psum += __shfl_xor(psum, 32);
    l_run = l_run * sc_old + psum;
    m_run = m_new;

    // rescale O (lane's O rows are q' = l4*4+r -> stats live in lane q')
    float scr[4];
#pragma unroll
    for (int r = 0; r < 4; ++r) scr[r] = __shfl(sc_old, l4 * 4 + r);
#pragma unroll
    for (int df = 0; df < 8; ++df)
#pragma unroll
      for (int r = 0; r < 4; ++r) O[df][r] *= scr[r];

    // ---- P -> Ps [w*16+l15][k] (unit-swizzled by q&7) ----
    {
      const int row = w * 16 + l15;
#pragma unroll
      for (int j = 0; j < 16; ++j) {
        const int k = (j >> 2) * 16 + l4 * 4 + (j & 3);
        Ps[row * 80 + (((k >> 3) ^ (l15 & 7)) << 3) + (k & 7)] = pb[j];
      }
    }

    // ---- O += P @ V : A = Ps rows (own q), B = Vs rows (d) ----
#pragma unroll
    for (int kc = 0; kc < 2; ++kc) {
      const int prow = w * 16 + l15;
      s16x8 aP = *(const s16x8*)&Ps[prow * 80 + ((((kc << 2) + l4) ^ (l15 & 7)) << 3)];
#pragma unroll
      for (int df = 0; df < 8; ++df) {
        const int d = df * 16 + l15;
        s16x8 bV = *(const s16x8*)&Vs[d * 64 + ((((kc << 2) + l4) ^ (d & 7)) << 3)];
        O[df] = __builtin_amdgcn_mfma_f32_16x16x32_bf16(aP, bV, O[df], 0, 0, 0);
      }
    }
  }

  // ---- epilogue: O /= l, write bf16 to xo ----
  const float inv_l = 1.0f / l_run;
  float invr[4];
#pragma unroll
  for (int r = 0; r < 4; ++r) invr[r] = __shfl(inv_l, l4 * 4 + r);
#pragma unroll
  for (int df = 0; df < 8; ++df)
#pragma unroll
    for (int r = 0; r < 4; ++r) {
      const int row = qb * 64 + w * 16 + l4 * 4 + r;
      xo[((size_t)(b * T_) + row) * D_ + hh * HD_ + df * 16 + l15] =
          f2bf(O[df][r] * invr[r]);
    }
}

// ---------------------------------------------------------------------------
// 256x256 8-phase GEMM for the logits layer (T2+T3+T4+T5, m201 template).
// ---------------------------------------------------------------------------
__global__ __launch_bounds__(512, 2)
void gemm8_logits(const u16* __restrict__ A, const u16* __restrict__ Bw,
                  const float* __restrict__ bias, float* __restrict__ C)
{
  int flat = blockIdx.x;
  int swz = (flat & 7) * 125 + (flat >> 3);
  const int bx = swz & 7;
  const int by = swz >> 3;
  const int m0 = bx << 8, n0 = by << 8;

  __shared__ __align__(16) u16 lds[65536];   // 128 KiB

  const int tid = threadIdx.x, lane = tid & 63, wave = tid >> 6;
  const int wm = wave >> 2, wn = wave & 3;
  const int l15 = lane & 15, l4 = lane >> 4;

  f32x4 acc[8][4];
  const f32x4 z4 = {0.f, 0.f, 0.f, 0.f};
#pragma unroll
  for (int i = 0; i < 8; ++i)
#pragma unroll
    for (int j = 0; j < 4; ++j) acc[i][j] = z4;

  auto stg = [&](const u16* G, int rowbase, int slot, int kt, int kh) {
    if (kt >= 16) return;
#pragma unroll
    for (int r = 0; r < 2; ++r) {
      const int u = r * 512 + (wave << 6) + lane;
      const int rw = u >> 2, ks = u & 3;
      const int ksw = ks ^ ((rw >> 1) & 3);
      const u16* src = G + (size_t)(rowbase + rw) * 1024 + (kt << 6) + (kh << 5) + (ksw << 3);
      gload16(src, &lds[slot + r * 4096 + (wave << 9)]);
    }
  };

  s16x8 af[4], bfr[4];

#define LDA4(bb, kk, mh)                                                      \
  {                                                                           \
    _Pragma("unroll") for (int f = 0; f < 4; ++f) {                           \
      const int rw = wm * 128 + (mh) * 64 + f * 16 + l15;                     \
      af[f] = *(const s16x8*)&lds[(bb) + (kk) * 8192 + rw * 32 +              \
                                  ((l4 ^ ((rw >> 1) & 3)) << 3)];             \
    }                                                                         \
  }
#define LDB4(bb, kk)                                                          \
  {                                                                           \
    _Pragma("unroll") for (int f = 0; f < 4; ++f) {                           \
      const int rn = wn * 64 + f * 16 + l15;                                  \
      bfr[f] = *(const s16x8*)&lds[(bb) + 16384 + (kk) * 8192 + rn * 32 +     \
                                   ((l4 ^ ((rn >> 1) & 3)) << 3)];            \
    }                                                                         \
  }
#define MFMA16(mh)                                                            \
  {                                                                           \
    __builtin_amdgcn_s_barrier();                                             \
    asm volatile("s_waitcnt lgkmcnt(0)" ::: "memory");                        \
    __builtin_amdgcn_sched_barrier(0);                                        \
    __builtin_amdgcn_s_setprio(1);                                            \
    _Pragma("unroll") for (int f = 0; f < 4; ++f)                             \
      _Pragma("unroll") for (int nf = 0; nf < 4; ++nf)                        \
        acc[(mh) * 4 + f][nf] = __builtin_amdgcn_mfma_f32_16x16x32_bf16(      \
            af[f], bfr[nf], acc[(mh) * 4 + f][nf], 0, 0, 0);                  \
    __builtin_amdgcn_s_setprio(0);                                            \
  }
#define BAR() __builtin_amdgcn_s_barrier()
#define VM4() asm volatile("s_waitcnt vmcnt(4)" ::: "memory")

  stg(A,  m0, 0,             0, 0);
  stg(Bw, n0, 16384,         0, 0);
  stg(A,  m0, 8192,          0, 1);
  stg(Bw, n0, 16384 + 8192,  0, 1);
  stg(A,  m0, 32768,         1, 0);
  stg(Bw, n0, 32768 + 16384, 1, 0);
  VM4();
  BAR();

  for (int i = 0; i < 8; ++i) {
    const int t = 2 * i;
    LDA4(0, 0, 0); LDB4(0, 0);
    stg(A, m0, 32768 + 8192, t + 1, 1);
    MFMA16(0); BAR();
    LDA4(0, 0, 1);
    stg(Bw, n0, 32768 + 24576, t + 1, 1);
    MFMA16(1); BAR();
    LDA4(0, 1, 0); LDB4(0, 1);
    stg(A, m0, 0, t + 2, 0);
    MFMA16(0); BAR();
    LDA4(0, 1, 1);
    stg(Bw, n0, 16384, t + 2, 0);
    MFMA16(1); VM4(); BAR();
    LDA4(32768, 0, 0); LDB4(32768, 0);
    stg(A, m0, 8192, t + 2, 1);
    MFMA16(0); BAR();
    LDA4(32768, 0, 1);
    stg(Bw, n0, 16384 + 8192, t + 2, 1);
    MFMA16(1); BAR();
    LDA4(32768, 1, 0); LDB4(32768, 1);
    stg(A, m0, 32768, t + 3, 0);
    MFMA16(0); BAR();
    LDA4(32768, 1, 1);
    stg(Bw, n0, 32768 + 16384, t + 3, 0);
    MFMA16(1); VM4(); BAR();
  }
#undef LDA4
#undef LDB4
#undef MFMA16
#undef BAR
#undef VM4

  float bv[4];
#pragma unroll
  for (int nf = 0; nf < 4; ++nf) bv[nf] = bias[n0 + wn * 64 + nf * 16 + l15];
#pragma unroll
  for (int mf = 0; mf < 8; ++mf) {
    const int row0 = m0 + wm * 128 + mf * 16 + l4 * 4;
#pragma unroll
    for (int nf = 0; nf < 4; ++nf) {
      const int col = n0 + wn * 64 + nf * 16 + l15;
#pragma unroll
      for (int r = 0; r < 4; ++r)
        C[(size_t)(row0 + r) * V_ + col] = acc[mf][nf][r] + bv[nf];
    }
  }
}

// ---------------------------------------------------------------------------
// LayerNorm: f32 in -> bf16 out. One block per row of 1024.
// ---------------------------------------------------------------------------
__global__ __launch_bounds__(256)
void ln_bf16(const float* __restrict__ x, const float* __restrict__ g,
             const float* __restrict__ b, u16* __restrict__ y)
{
  __shared__ float red[8];
  const int row = blockIdx.x, tid = threadIdx.x;
  f32x4 v = *(const f32x4*)&x[(size_t)row * D_ + tid * 4];
  float s  = v[0] + v[1] + v[2] + v[3];
  float s2 = v[0]*v[0] + v[1]*v[1] + v[2]*v[2] + v[3]*v[3];
#pragma unroll
  for (int off = 32; off > 0; off >>= 1) {
    s  += __shfl_xor(s, off);
    s2 += __shfl_xor(s2, off);
  }
  if ((tid & 63) == 0) { red[tid >> 6] = s; red[4 + (tid >> 6)] = s2; }
  __syncthreads();
  s  = red[0] + red[1] + red[2] + red[3];
  s2 = red[4] + red[5] + red[6] + red[7];
  const float mean = s * (1.0f / D_);
  const float var  = s2 * (1.0f / D_) - mean * mean;
  const float rs   = rsqrtf(var + 1e-5f);
  f32x4 gg = *(const f32x4*)&g[tid * 4];
  f32x4 bb = *(const f32x4*)&b[tid * 4];
  u16 o[4];
#pragma unroll
  for (int j = 0; j < 4; ++j) o[j] = f2bf((v[j] - mean) * rs * gg[j] + bb[j]);
  *(s16x4*)&y[(size_t)row * D_ + tid * 4] = *(const s16x4*)o;
}

// ---------------------------------------------------------------------------
// Embedding: h[row] = tok_emb[x[row]] + pos_emb[row % T]   (f32 out)
// ---------------------------------------------------------------------------
__global__ __launch_bounds__(256)
void embed_kernel(const int* __restrict__ x, const float* __restrict__ tok,
                  const float* __restrict__ pos, float* __restrict__ h)
{
  const int row = blockIdx.x, tid = threadIdx.x;
  const int t = row & (T_ - 1);
  const int id = x[row];
  f32x4 a = *(const f32x4*)&tok[(size_t)id * D_ + tid * 4];
  f32x4 p = *(const f32x4*)&pos[(size_t)t * D_ + tid * 4];
  f32x4 o = {a[0] + p[0], a[1] + p[1], a[2] + p[2], a[3] + p[3]};
  *(f32x4*)&h[(size_t)row * D_ + tid * 4] = o;
}

// ---------------------------------------------------------------------------
extern "C" void kernel_launch(void* const* d_in, const int* in_sizes, int n_in,
                              void* d_out, int out_size, void* d_ws, size_t ws_size,
                              hipStream_t stream)
{
  (void)in_sizes; (void)n_in; (void)out_size; (void)ws_size;
  const int*   x     = (const int*)  d_in[0];
  const float* tok   = (const float*)d_in[1];
  const float* pos   = (const float*)d_in[2];
  const float* ln1_g = (const float*)d_in[3];
  const float* ln1_b = (const float*)d_in[4];
  const float* wqkv  = (const float*)d_in[5];
  const float* bqkv  = (const float*)d_in[6];
  const float* wo    = (const float*)d_in[7];
  const float* bo    = (const float*)d_in[8];
  const float* ln2_g = (const float*)d_in[9];
  const float* ln2_b = (const float*)d_in[10];
  const float* wfc   = (const float*)d_in[11];
  const float* wfc2  = (const float*)d_in[12];
  const float* fn_g  = (const float*)d_in[13];
  const float* fn_b  = (const float*)d_in[14];
  const float* wout  = (const float*)d_in[15];
  const float* bout  = (const float*)d_in[16];
  float* out = (float*)d_out;

  // ws layout (88.1 MB total) — same as round 2/3:
  // h f32 | xn bf16 | Wq | Wo | Wf1 | Wf2 | qkv | Vt | S(fc1)
  // woutT (65.5MB) overlays Wq.. after the layers.
  float* h  = (float*)d_ws;                 // 2048*1024 f32
  u16* xn   = (u16*)(h + (size_t)M_ * D_);  // 2048*1024
  u16* Wq   = xn  + (size_t)M_ * D_;        // 3072*1024
  u16* Wo   = Wq  + (size_t)3 * D_ * D_;    // 1024*1024
  u16* Wf1  = Wo  + (size_t)D_ * D_;        // 4096*1024
  u16* Wf2  = Wf1 + (size_t)4 * D_ * D_;    // 1024*4096
  u16* qkv  = Wf2 + (size_t)4 * D_ * D_;    // 2048*3072
  u16* Vt   = qkv + (size_t)M_ * 3 * D_;    // 2*1024*1024  [b][hh*128+d][t]
  u16* S    = Vt  + (size_t)2 * T_ * D_;    // fc1 buffer (2048*4096)
  u16* WoutT = Wq;                          // 32000*1024 overlay

  embed_kernel<<<M_, 256, 0, stream>>>(x, tok, pos, h);

  for (int l = 0; l < L_; ++l) {
    convT_kernel<1><<<dim3(48, 16, 1), 256, 0, stream>>>(
        wqkv + (size_t)l * D_ * 3 * D_, Wq, 3 * D_, D_, 0, 0);
    convT_kernel<1><<<dim3(16, 16, 1), 256, 0, stream>>>(
        wo + (size_t)l * D_ * D_, Wo, D_, D_, 0, 0);
    convT_kernel<1><<<dim3(64, 16, 1), 256, 0, stream>>>(
        wfc + (size_t)l * D_ * 4 * D_, Wf1, 4 * D_, D_, 0, 0);
    convT_kernel<1><<<dim3(16, 64, 1), 256, 0, stream>>>(
        wfc2 + (size_t)l * 4 * D_ * D_, Wf2, D_, 4 * D_, 0, 0);

    // ln1 -> xn (bf16)
    ln_bf16<<<M_, 256, 0, stream>>>(h, ln1_g + l * D_, ln1_b + l * D_, xn);
    // qkv = xn @ WqT + bqkv
    gemm2<128, 0, 1, 0><<<dim3(16, 24), 256, 0, stream>>>(
        xn, Wq, bqkv + l * 3 * D_, nullptr, qkv, D_, D_, D_, 3 * D_, 1.0f);
    // V^T per batch: qkv cols 2048.. -> Vt[b][hh*128+d][t]
    convT_kernel<0><<<dim3(16, 16, 2), 256, 0, stream>>>(
        qkv + 2 * D_, Vt, 3 * D_, T_, (long)T_ * 3 * D_, (long)T_ * D_);
    // fused causal attention -> xn (bf16)
    flash_attn<<<dim3(16, 16), 256, 0, stream>>>(qkv, Vt, xn);
    // h += attn @ WoT + bo
    gemm2<64, 0, 1, 2><<<dim3(32, 8), 256, 0, stream>>>(
        xn, Wo, bo + l * D_, h, h, D_, D_, D_, D_, 1.0f);
    // ln2 -> xn
    ln_bf16<<<M_, 256, 0, stream>>>(h, ln2_g + l * D_, ln2_b + l * D_, xn);
    // fc1 = gelu(xn @ Wf1T)
    gemm2<128, 1, 0, 0><<<dim3(16, 32), 256, 0, stream>>>(
        xn, Wf1, nullptr, nullptr, S, D_, D_, D_, 4 * D_, 1.0f);
    // h += fc1 @ Wf2T
    gemm2<64, 0, 0, 2><<<dim3(32, 8), 256, 0, stream>>>(
        S, Wf2, nullptr, h, h, 4 * D_, 4 * D_, 4 * D_, D_, 1.0f);
  }

  // final LN -> xn; wout^T into overlay; logits via 8-phase 256^2 kernel
  ln_bf16<<<M_, 256, 0, stream>>>(h, fn_g, fn_b, xn);
  convT_kernel<1><<<dim3(500, 16, 1), 256, 0, stream>>>(
      wout, WoutT, V_, D_, 0, 0);
  gemm8_logits<<<1000, 512, 0, stream>>>(xn, WoutT, bout, out);
}